// Round 1
// baseline (1997.196 us; speedup 1.0000x reference)
//
#include <hip/hip_runtime.h>
#include <hip/hip_bf16.h>
#include <math.h>

using short8 = __attribute__((ext_vector_type(8))) short;
using f32x4  = __attribute__((ext_vector_type(4))) float;
using bf16_t = __hip_bfloat16;

#define DI __device__ __forceinline__

static constexpr float SCALE_ = 0.08838834764831845f;  // 1/sqrt(128)

DI void async16(const void* g, void* l) {
  __builtin_amdgcn_global_load_lds((const __attribute__((address_space(1))) void*)g,
                                   (__attribute__((address_space(3))) void*)l, 16, 0, 0);
}

DI float wave_red_sum(float v) {
#pragma unroll
  for (int o = 32; o > 0; o >>= 1) v += __shfl_down(v, o, 64);
  return v;
}
DI float wave_red_max(float v) {
#pragma unroll
  for (int o = 32; o > 0; o >>= 1) v = fmaxf(v, __shfl_down(v, o, 64));
  return v;
}

DI unsigned short f2bu(float f) {
  union { bf16_t b; unsigned short u; } cv;
  cv.b = __float2bfloat16(f);
  return cv.u;
}

// ---------------------------------------------------------------------------
// C[M,N] = A[M,K] * B[N,K]^T  (bf16 inputs, fp32 accumulate)
// 128x128 block, 256 threads (4 waves), each wave 64x64 via 4x4 MFMA 16x16x32.
// Batched over blockIdx.z with element strides sA,sB,sC.
// mode 0: Cf[idx]=acc   mode 1: Cf[idx]=acc+Rf[idx]   mode 2: Cb[idx]=bf16(acc)
// causal 1: skip blocks fully above diagonal (scores)
// causal 2: clip K to bm0+128 (PV with causal-zeroed P)
// ---------------------------------------------------------------------------
__global__ __launch_bounds__(256)
void gemm_bt(const short* __restrict__ A, const short* __restrict__ B,
             float* __restrict__ Cf, bf16_t* __restrict__ Cb, const float* __restrict__ Rf,
             int M, int N, int K, int ldc, int c_col_off, int c_col_zstride,
             long sA, long sB, long sC, int mode, int causal)
{
  const int bn0 = blockIdx.x * 128;
  const int bm0 = blockIdx.y * 128;
  if (causal == 1 && bn0 >= bm0 + 128) return;
  const int kmax = (causal == 2) ? ((bm0 + 128 < K) ? bm0 + 128 : K) : K;

  __shared__ short As[128 * 32];
  __shared__ short Bs[128 * 32];

  const int t = threadIdx.x;
  const int z = blockIdx.z;
  const short* Az = A + (long)z * sA;
  const short* Bz = B + (long)z * sB;

  const int lane = t & 63;
  const int wave = t >> 6;
  const int wm = (wave & 1) << 6;   // 0 or 64 (row half)
  const int wn = (wave >> 1) << 6;  // 0 or 64 (col half)
  const int q = lane >> 4;          // 0..3
  const int r = lane & 15;          // 0..15

  f32x4 zero = {0.f, 0.f, 0.f, 0.f};
  f32x4 acc[4][4];
#pragma unroll
  for (int i = 0; i < 4; ++i)
#pragma unroll
    for (int j = 0; j < 4; ++j) acc[i][j] = zero;

  const int srow = t >> 2;        // 0..63
  const int skq  = (t & 3) << 3;  // 0,8,16,24 (shorts)
  char* aW = (char*)As + wave * 1024;
  char* bW = (char*)Bs + wave * 1024;

  const short* arow0 = Az + (long)(bm0 + srow) * K + skq;
  const short* arow1 = Az + (long)(bm0 + 64 + srow) * K + skq;
  const short* brow0 = Bz + (long)(bn0 + srow) * K + skq;
  const short* brow1 = Bz + (long)(bn0 + 64 + srow) * K + skq;

  for (int k0 = 0; k0 < kmax; k0 += 32) {
    __syncthreads();
    async16(arow0 + k0, aW);
    async16(arow1 + k0, aW + 4096);
    async16(brow0 + k0, bW);
    async16(brow1 + k0, bW + 4096);
    __syncthreads();
    short8 av[4], bv[4];
#pragma unroll
    for (int i = 0; i < 4; ++i)
      av[i] = *(const short8*)(&As[(wm + i * 16 + r) * 32 + q * 8]);
#pragma unroll
    for (int i = 0; i < 4; ++i)
      bv[i] = *(const short8*)(&Bs[(wn + i * 16 + r) * 32 + q * 8]);
#pragma unroll
    for (int i = 0; i < 4; ++i)
#pragma unroll
      for (int j = 0; j < 4; ++j)
        acc[i][j] = __builtin_amdgcn_mfma_f32_16x16x32_bf16(av[i], bv[j], acc[i][j], 0, 0, 0);
  }

  const long zc = (long)z * sC;
  const int colb = c_col_off + z * c_col_zstride + bn0 + wn + r;
#pragma unroll
  for (int i = 0; i < 4; ++i) {
    const int row0 = bm0 + wm + i * 16 + q * 4;
#pragma unroll
    for (int j = 0; j < 4; ++j) {
      const int col = colb + j * 16;
#pragma unroll
      for (int e = 0; e < 4; ++e) {
        const long idx = zc + (long)(row0 + e) * ldc + col;
        const float vv = acc[i][j][e];
        if (mode == 0)      Cf[idx] = vv;
        else if (mode == 1) Cf[idx] = vv + Rf[idx];
        else                Cb[idx] = __float2bfloat16(vv);
      }
    }
  }
}

// ---------------------------------------------------------------------------
// Q4 dequant (bit-exact vs reference up to final bf16 cast):
// per 32-elem group along K: s=max|w|/7+1e-12; q=clip(rint(w/s),-8,7); out=q*s
// ---------------------------------------------------------------------------
__global__ __launch_bounds__(256)
void dequant_q4(const float* __restrict__ W, bf16_t* __restrict__ O, int ngroups)
{
  const int g = blockIdx.x * 256 + threadIdx.x;
  if (g >= ngroups) return;
  const float4* p = (const float4*)(W + (long)g * 32);
  float4 v[8];
  float amax = 0.f;
#pragma unroll
  for (int i = 0; i < 8; ++i) {
    v[i] = p[i];
    amax = fmaxf(amax, fmaxf(fmaxf(fabsf(v[i].x), fabsf(v[i].y)),
                             fmaxf(fabsf(v[i].z), fabsf(v[i].w))));
  }
  const float s = amax / 7.0f + 1e-12f;
  bf16_t* o = O + (long)g * 32;
#pragma unroll
  for (int i = 0; i < 8; ++i) {
    o[i * 4 + 0] = __float2bfloat16(fminf(fmaxf(rintf(v[i].x / s), -8.f), 7.f) * s);
    o[i * 4 + 1] = __float2bfloat16(fminf(fmaxf(rintf(v[i].y / s), -8.f), 7.f) * s);
    o[i * 4 + 2] = __float2bfloat16(fminf(fmaxf(rintf(v[i].z / s), -8.f), 7.f) * s);
    o[i * 4 + 3] = __float2bfloat16(fminf(fmaxf(rintf(v[i].w / s), -8.f), 7.f) * s);
  }
}

__global__ __launch_bounds__(256)
void embed_k(const int* __restrict__ ids, const float* __restrict__ E, float* __restrict__ H)
{
  const int idx = blockIdx.x * 256 + threadIdx.x;  // 1024*512 float4
  const int s = idx >> 9, c = idx & 511;
  ((float4*)H)[idx] = ((const float4*)(E + (long)ids[s] * 2048))[c];
}

__global__ __launch_bounds__(256)
void rmsnorm_k(const float* __restrict__ X, const float* __restrict__ W, bf16_t* __restrict__ Y)
{
  const int row = blockIdx.x;
  const int t = threadIdx.x;
  const float4* x4 = (const float4*)(X + (long)row * 2048);
  const float4 v0 = x4[t], v1 = x4[t + 256];
  float ss = v0.x * v0.x + v0.y * v0.y + v0.z * v0.z + v0.w * v0.w
           + v1.x * v1.x + v1.y * v1.y + v1.z * v1.z + v1.w * v1.w;
  ss = wave_red_sum(ss);
  __shared__ float sb[4];
  if ((t & 63) == 0) sb[t >> 6] = ss;
  __syncthreads();
  const float tot = sb[0] + sb[1] + sb[2] + sb[3];
  const float rinv = 1.0f / sqrtf(tot * (1.0f / 2048.0f) + 1e-5f);
  const float4* w4 = (const float4*)W;
  const float4 w0 = w4[t], w1 = w4[t + 256];
  ushort4* y4 = (ushort4*)(Y + (long)row * 2048);
  y4[t]       = make_ushort4(f2bu(v0.x * w0.x * rinv), f2bu(v0.y * w0.y * rinv),
                             f2bu(v0.z * w0.z * rinv), f2bu(v0.w * w0.w * rinv));
  y4[t + 256] = make_ushort4(f2bu(v1.x * w1.x * rinv), f2bu(v1.y * w1.y * rinv),
                             f2bu(v1.z * w1.z * rinv), f2bu(v1.w * w1.w * rinv));
}

// X: fp32 rows of qkvf (stride 6144), pointer pre-offset to q or k columns.
// Y: bf16 [NH][S][HD]
__global__ __launch_bounds__(256)
void rope_k(const float* __restrict__ X, bf16_t* __restrict__ Y, const int* __restrict__ posp)
{
  const int s = blockIdx.x;
  const float pos = (float)(posp[0] + s);
#pragma unroll
  for (int i = 0; i < 4; ++i) {
    const int vtx = threadIdx.x + i * 256;
    const int d = vtx & 63, h = vtx >> 6;
    const float inv_freq = expf((float)d * -0.14391156831212787f);  // ln(10000)/64
    const float ang = pos * inv_freq;
    const float c = cosf(ang), sn = sinf(ang);
    const float x1 = X[(long)s * 6144 + h * 128 + d];
    const float x2 = X[(long)s * 6144 + h * 128 + d + 64];
    bf16_t* yb = Y + ((long)h * 1024 + s) * 128 + d;
    yb[0]  = __float2bfloat16(x1 * c - x2 * sn);
    yb[64] = __float2bfloat16(x2 * c + x1 * sn);
  }
}

// X: fp32 v-columns of qkvf (pre-offset, stride 6144) -> Y bf16 [NH][HD][S]
__global__ __launch_bounds__(256)
void transv_k(const float* __restrict__ X, bf16_t* __restrict__ Y)
{
  const int s = blockIdx.x * 256 + threadIdx.x;
  const int d = blockIdx.y, h = blockIdx.z;
  Y[((long)(h * 128 + d)) * 1024 + s] =
      __float2bfloat16(X[(long)s * 6144 + h * 128 + d]);
}

// scores fp32 [NH][S][1024] -> P bf16 (masked softmax, zero-filled to block edge)
__global__ __launch_bounds__(256)
void softmax_k(const float* __restrict__ Sc, bf16_t* __restrict__ P, const int* __restrict__ posp)
{
  const int s = blockIdx.x, h = blockIdx.y, t = threadIdx.x;
  const float* row = Sc + ((long)h * 1024 + s) * 1024;
  bf16_t* prow = P + ((long)h * 1024 + s) * 1024;
  int n = posp[0] + s + 1;
  if (n > 1024) n = 1024;
  float v[4];
  float mx = -1e30f;
#pragma unroll
  for (int i = 0; i < 4; ++i) {
    const int j = t + i * 256;
    v[i] = (j < n) ? row[j] * SCALE_ : -1e30f;
    mx = fmaxf(mx, v[i]);
  }
  mx = wave_red_max(mx);
  __shared__ float sb[4];
  __shared__ float sb2[4];
  if ((t & 63) == 0) sb[t >> 6] = mx;
  __syncthreads();
  mx = fmaxf(fmaxf(sb[0], sb[1]), fmaxf(sb[2], sb[3]));
  float sum = 0.f;
#pragma unroll
  for (int i = 0; i < 4; ++i) {
    const int j = t + i * 256;
    v[i] = (j < n) ? expf(v[i] - mx) : 0.f;
    sum += v[i];
  }
  sum = wave_red_sum(sum);
  if ((t & 63) == 0) sb2[t >> 6] = sum;
  __syncthreads();
  const float inv = 1.0f / (sb2[0] + sb2[1] + sb2[2] + sb2[3]);
  const int nstore = ((s >> 7) + 1) << 7;  // PV reads up to row-block edge
#pragma unroll
  for (int i = 0; i < 4; ++i) {
    const int j = t + i * 256;
    if (j < nstore) prow[j] = __float2bfloat16(v[i] * inv);
  }
}

// UG fp32 [S][11264] (up | gate) -> U bf16 [S][5632]: u * silu(g)
__global__ __launch_bounds__(256)
void silu_k(const float* __restrict__ UG, bf16_t* __restrict__ U)
{
  const int j = blockIdx.x * 256 + threadIdx.x;
  const int s = blockIdx.y;
  const float u = UG[(long)s * 11264 + j];
  const float g = UG[(long)s * 11264 + 5632 + j];
  U[(long)s * 5632 + j] = __float2bfloat16(u * g / (1.0f + expf(-g)));
}

// ---------------------------------------------------------------------------
extern "C" void kernel_launch(void* const* d_in, const int* in_sizes, int n_in,
                              void* d_out, int out_size, void* d_ws, size_t ws_size,
                              hipStream_t stream)
{
  (void)in_sizes; (void)n_in; (void)out_size; (void)ws_size;
  const int*   ids     = (const int*)  d_in[0];
  const int*   posp    = (const int*)  d_in[3];
  const float* embed_w = (const float*)d_in[4];
  const float* in_ln   = (const float*)d_in[5];
  const float* post_ln = (const float*)d_in[6];
  const float* fin_ln  = (const float*)d_in[7];
  const float* q_w     = (const float*)d_in[8];
  const float* k_w     = (const float*)d_in[9];
  const float* v_w     = (const float*)d_in[10];
  const float* o_w     = (const float*)d_in[11];
  const float* gate_w  = (const float*)d_in[12];
  const float* up_w    = (const float*)d_in[13];
  const float* down_w  = (const float*)d_in[14];
  const float* lm_w    = (const float*)d_in[15];
  float* out = (float*)d_out;

  char* ws = (char*)d_ws;
  size_t off = 0;
  auto alloc = [&](size_t b) -> char* {
    char* p = ws + off;
    off += (b + 255) & ~(size_t)255;
    return p;
  };
  bf16_t* deq  = (bf16_t*)alloc(65536000);        // up to 16000x2048 bf16
  float*  hbuf = (float*) alloc(1024L * 2048 * 4);
  float*  abuf = (float*) alloc(1024L * 2048 * 4);
  bf16_t* xb   = (bf16_t*)alloc(1024L * 2048 * 2);
  bf16_t* qr   = (bf16_t*)alloc(16L * 1024 * 128 * 2);
  bf16_t* kr   = (bf16_t*)alloc(16L * 1024 * 128 * 2);
  bf16_t* vt   = (bf16_t*)alloc(16L * 1024 * 128 * 2);
  bf16_t* ctx  = (bf16_t*)alloc(1024L * 2048 * 2);
  char*   big  = alloc(100663296);                // scores(64MB)+P(32MB) / qkvf / ug+ub
  float*  qkvf   = (float*)big;                   // [1024][6144]
  float*  scores = (float*)big;                   // [16][1024][1024] fp32
  bf16_t* P      = (bf16_t*)(big + 67108864);     // [16][1024][1024] bf16
  float*  ugf    = (float*)big;                   // [1024][11264]
  bf16_t* ub     = (bf16_t*)(big + 46137344);     // [1024][5632]

  const dim3 B256(256);
  auto gemm = [&](const void* A, const void* Bw, float* Cf, bf16_t* Cb, const float* Rf,
                  int M, int N, int K, int ldc, int coloff, int colz,
                  long sA, long sB, long sC, int mode, int causal, int Z) {
    gemm_bt<<<dim3(N / 128, M / 128, Z), B256, 0, stream>>>(
        (const short*)A, (const short*)Bw, Cf, Cb, Rf,
        M, N, K, ldc, coloff, colz, sA, sB, sC, mode, causal);
  };

  embed_k<<<2048, B256, 0, stream>>>(ids, embed_w, hbuf);

  for (int l = 0; l < 2; ++l) {
    rmsnorm_k<<<1024, B256, 0, stream>>>(hbuf, in_ln + l * 2048, xb);
    // fused QKV: dequant q,k,v stacked -> B [6144,2048]
    dequant_q4<<<512, B256, 0, stream>>>(q_w + (long)l * 2048 * 2048, deq,               131072);
    dequant_q4<<<512, B256, 0, stream>>>(k_w + (long)l * 2048 * 2048, deq + 2048L * 2048, 131072);
    dequant_q4<<<512, B256, 0, stream>>>(v_w + (long)l * 2048 * 2048, deq + 4096L * 2048, 131072);
    gemm(xb, deq, qkvf, nullptr, nullptr, 1024, 6144, 2048, 6144, 0, 0, 0, 0, 0, 0, 0, 1);
    rope_k<<<1024, B256, 0, stream>>>(qkvf,        qr, posp);
    rope_k<<<1024, B256, 0, stream>>>(qkvf + 2048, kr, posp);
    transv_k<<<dim3(4, 128, 16), B256, 0, stream>>>(qkvf + 4096, vt);
    // scores = q k^T (batched over heads, causal block-skip)
    gemm(qr, kr, scores, nullptr, nullptr, 1024, 1024, 128, 1024, 0, 0,
         131072L, 131072L, 1048576L, 0, 1, 16);
    softmax_k<<<dim3(1024, 16), B256, 0, stream>>>(scores, P, posp);
    // ctx = P V  (K clipped causally), written bf16 into [S][NH*HD]
    gemm(P, vt, nullptr, ctx, nullptr, 1024, 128, 1024, 2048, 0, 128,
         1048576L, 131072L, 0L, 2, 2, 16);
    // o-proj + residual
    dequant_q4<<<512, B256, 0, stream>>>(o_w + (long)l * 2048 * 2048, deq, 131072);
    gemm(ctx, deq, abuf, nullptr, hbuf, 1024, 2048, 2048, 2048, 0, 0, 0, 0, 0, 1, 0, 1);
    rmsnorm_k<<<1024, B256, 0, stream>>>(abuf, post_ln + l * 2048, xb);
    // fused up|gate
    dequant_q4<<<1408, B256, 0, stream>>>(up_w   + (long)l * 5632 * 2048, deq,                360448);
    dequant_q4<<<1408, B256, 0, stream>>>(gate_w + (long)l * 5632 * 2048, deq + 5632L * 2048, 360448);
    gemm(xb, deq, ugf, nullptr, nullptr, 1024, 11264, 2048, 11264, 0, 0, 0, 0, 0, 0, 0, 1);
    silu_k<<<dim3(22, 1024), B256, 0, stream>>>(ugf, ub);
    // down + residual
    dequant_q4<<<1408, B256, 0, stream>>>(down_w + (long)l * 2048 * 5632, deq, 360448);
    gemm(ub, deq, hbuf, nullptr, abuf, 1024, 2048, 5632, 2048, 0, 0, 0, 0, 0, 1, 0, 1);
  }

  rmsnorm_k<<<1024, B256, 0, stream>>>(hbuf, fin_ln, xb);
  // lm_head in two 16000-row chunks (keeps dequant buffer at 65.5 MB)
  for (int c = 0; c < 2; ++c) {
    dequant_q4<<<4000, B256, 0, stream>>>(lm_w + (long)c * 16000 * 2048, deq, 1024000);
    gemm(xb, deq, out, nullptr, nullptr, 1024, 16000, 2048, 32000, c * 16000, 0,
         0, 0, 0, 0, 0, 1);
  }
}